// Round 5
// baseline (359.452 us; speedup 1.0000x reference)
//
#include <hip/hip_runtime.h>
#include <hip/hip_bf16.h>
#include <math.h>

#define B_    8
#define OLEN  1024
#define ILEN  4096
#define HDIM  256
#define LDA   40   // fallback-path LDS row stride (shorts)

typedef __attribute__((ext_vector_type(8))) short bf16x8;
typedef __attribute__((ext_vector_type(4))) float f32x4;

__device__ inline unsigned pk_bf16(float x, float y) {
  union { __hip_bfloat162 h; unsigned u; } c;
  c.h = __float22bfloat162_rn(make_float2(x, y));
  return c.u;
}
__device__ inline short f2bf(float x) {
  union { __hip_bfloat16 h; short s; } c;
  c.h = __float2bfloat16(x);
  return c.s;
}

struct HiLo { uint4 hi, lo; };
__device__ inline HiLo split8(const float* __restrict__ p) {
  float4 v0 = *(const float4*)p;
  float4 v1 = *(const float4*)(p + 4);
  float f[8] = {v0.x, v0.y, v0.z, v0.w, v1.x, v1.y, v1.z, v1.w};
  unsigned hu[8]; float lo[8];
#pragma unroll
  for (int i = 0; i < 8; ++i) {
    unsigned u = __float_as_uint(f[i]);
    hu[i] = u & 0xffff0000u;
    lo[i] = f[i] - __uint_as_float(hu[i]);
  }
  HiLo r;
  r.hi = make_uint4((hu[0] >> 16) | hu[1], (hu[2] >> 16) | hu[3],
                    (hu[4] >> 16) | hu[5], (hu[6] >> 16) | hu[7]);
  r.lo = make_uint4(pk_bf16(lo[0], lo[1]), pk_bf16(lo[2], lo[3]),
                    pk_bf16(lo[4], lo[5]), pk_bf16(lo[6], lo[7]));
  return r;
}

__device__ inline void gl_lds16(const void* g, void* l) {
  __builtin_amdgcn_global_load_lds(
      (const __attribute__((address_space(1))) unsigned*)g,
      (__attribute__((address_space(3))) unsigned*)(l), 16, 0, 0);
}

// ---------------------------------------------------------------------------
// P0: Q -> Qhi/Qlo bf16 (linear).
// ---------------------------------------------------------------------------
__global__ __launch_bounds__(256) void k_prep_q(const float* __restrict__ Q,
                                                short* __restrict__ Qhi,
                                                short* __restrict__ Qlo) {
  const size_t idx = ((size_t)blockIdx.x * 256 + threadIdx.x) * 8;
  HiLo r = split8(&Q[idx]);
  *(uint4*)&Qhi[idx] = r.hi;
  *(uint4*)&Qlo[idx] = r.lo;
}

// ---------------------------------------------------------------------------
// P1: E -> Ehi/Elo (linear) + ET bf16 RNE transposed [b][h][i]. E read once.
// ---------------------------------------------------------------------------
__global__ __launch_bounds__(256) void k_prep_e(const float* __restrict__ E,
                                                short* __restrict__ Ehi,
                                                short* __restrict__ Elo,
                                                short* __restrict__ ET) {
  const int it = blockIdx.x, ht = blockIdx.y, b = blockIdx.z;
  __shared__ short L[32][36];
  const int t = threadIdx.x;
  {
    const int i = t >> 3, h0 = (t & 7) * 4;
    const size_t gidx = ((size_t)(b * ILEN + it * 32 + i)) * HDIM + ht * 32 + h0;
    float4 v = *(const float4*)&E[gidx];
    float f[4] = {v.x, v.y, v.z, v.w};
    unsigned hs[4]; float lo[4];
#pragma unroll
    for (int j = 0; j < 4; ++j) {
      unsigned u = __float_as_uint(f[j]);
      hs[j] = u & 0xffff0000u;
      lo[j] = f[j] - __uint_as_float(hs[j]);
    }
    *(uint2*)&Ehi[gidx] = make_uint2((hs[0] >> 16) | hs[1], (hs[2] >> 16) | hs[3]);
    *(uint2*)&Elo[gidx] = make_uint2(pk_bf16(lo[0], lo[1]), pk_bf16(lo[2], lo[3]));
    L[h0 + 0][i] = f2bf(f[0]);
    L[h0 + 1][i] = f2bf(f[1]);
    L[h0 + 2][i] = f2bf(f[2]);
    L[h0 + 3][i] = f2bf(f[3]);
  }
  __syncthreads();
  {
    const int h = t >> 3, i0 = (t & 7) * 4;
    *(uint2*)&ET[((size_t)(b * HDIM + ht * 32 + h)) * ILEN + it * 32 + i0] =
        *(const uint2*)&L[h][i0];
  }
}

// ---------------------------------------------------------------------------
// K1: scores, split-bf16 3-term MFMA, 128x128 tile, KC=32 (unchanged R4).
// ---------------------------------------------------------------------------
__global__ __launch_bounds__(256) void k_scores_pre(
    const short* __restrict__ Qhi, const short* __restrict__ Qlo,
    const short* __restrict__ Ehi, const short* __restrict__ Elo,
    float* __restrict__ S) {
  const int it = blockIdx.x, ot = blockIdx.y, b = blockIdx.z;
  const size_t qoff = ((size_t)b * OLEN + ot * 128) * HDIM;
  const size_t eoff = ((size_t)b * ILEN + it * 128) * HDIM;

  __shared__ __align__(16) short Ah[128 * 32], Al[128 * 32];
  __shared__ __align__(16) short Bh[128 * 32], Bl[128 * 32];

  const int t = threadIdx.x;
  const int w = t >> 6, l = t & 63;
  const int la = l & 15, quad = l >> 4;
  const int mw = (w & 1) * 64, nw = (w >> 1) * 64;

  int sgoff[2], sloff[2];
#pragma unroll
  for (int j = 0; j < 2; ++j) {
    const int row = (w * 2 + j) * 16 + (l >> 2);
    const int c = (l & 3) ^ ((row >> 1) & 3);
    sgoff[j] = row * HDIM + c * 8;
    sloff[j] = ((w * 2 + j) * 64 + l) * 8;
  }

  f32x4 acc[4][4] = {};

  for (int kc = 0; kc < HDIM; kc += 32) {
#pragma unroll
    for (int j = 0; j < 2; ++j) {
      const size_t ga = qoff + sgoff[j] + kc;
      const size_t gb = eoff + sgoff[j] + kc;
      gl_lds16(&Qhi[ga], &Ah[sloff[j]]);
      gl_lds16(&Qlo[ga], &Al[sloff[j]]);
      gl_lds16(&Ehi[gb], &Bh[sloff[j]]);
      gl_lds16(&Elo[gb], &Bl[sloff[j]]);
    }
    __syncthreads();
    bf16x8 ah[4], al[4];
#pragma unroll
    for (int mi = 0; mi < 4; ++mi) {
      const int row = mw + mi * 16 + la;
      const int off = row * 32 + (quad ^ ((row >> 1) & 3)) * 8;
      ah[mi] = *(const bf16x8*)&Ah[off];
      al[mi] = *(const bf16x8*)&Al[off];
    }
#pragma unroll
    for (int ni = 0; ni < 4; ++ni) {
      const int row = nw + ni * 16 + la;
      const int off = row * 32 + (quad ^ ((row >> 1) & 3)) * 8;
      bf16x8 bh = *(const bf16x8*)&Bh[off];
      bf16x8 bl = *(const bf16x8*)&Bl[off];
#pragma unroll
      for (int mi = 0; mi < 4; ++mi) {
        acc[mi][ni] = __builtin_amdgcn_mfma_f32_16x16x32_bf16(ah[mi], bh, acc[mi][ni], 0, 0, 0);
        acc[mi][ni] = __builtin_amdgcn_mfma_f32_16x16x32_bf16(ah[mi], bl, acc[mi][ni], 0, 0, 0);
        acc[mi][ni] = __builtin_amdgcn_mfma_f32_16x16x32_bf16(al[mi], bh, acc[mi][ni], 0, 0, 0);
      }
    }
    __syncthreads();
  }

  float* Sb = S + ((size_t)b * OLEN + ot * 128) * (size_t)ILEN + it * 128;
#pragma unroll
  for (int mi = 0; mi < 4; ++mi)
#pragma unroll
    for (int ni = 0; ni < 4; ++ni)
#pragma unroll
      for (int r = 0; r < 4; ++r)
        Sb[(size_t)(mw + mi * 16 + quad * 4 + r) * ILEN + nw + ni * 16 + la] =
            acc[mi][ni][r];
}

// ---------------------------------------------------------------------------
// K2a: masked row softmax, fp32 out + fused bf16 copy for the context GEMM.
// ---------------------------------------------------------------------------
__global__ __launch_bounds__(256) void k_softmax_bf(float* __restrict__ A,
                                                    short* __restrict__ Pbf,
                                                    const int* __restrict__ len) {
  const int row = blockIdx.x;
  const int b   = row >> 10;
  const int L   = len[b];
  float* p = A + (size_t)row * ILEN;
  short* q = Pbf + (size_t)row * ILEN;
  const int t = threadIdx.x;

  float v[16];
#pragma unroll
  for (int k = 0; k < 4; ++k) {
    float4 x = *(const float4*)&p[4 * t + 1024 * k];
    v[4 * k + 0] = x.x; v[4 * k + 1] = x.y;
    v[4 * k + 2] = x.z; v[4 * k + 3] = x.w;
  }

  float m = -INFINITY;
#pragma unroll
  for (int k = 0; k < 4; ++k)
#pragma unroll
    for (int j = 0; j < 4; ++j) {
      const int i = 4 * t + 1024 * k + j;
      if (i < L) m = fmaxf(m, v[4 * k + j]);
    }
  for (int o = 32; o > 0; o >>= 1) m = fmaxf(m, __shfl_xor(m, o, 64));
  __shared__ float sm[4], ss[4];
  const int w = t >> 6;
  if ((t & 63) == 0) sm[w] = m;
  __syncthreads();
  m = fmaxf(fmaxf(sm[0], sm[1]), fmaxf(sm[2], sm[3]));

  float s = 0.f;
#pragma unroll
  for (int k = 0; k < 4; ++k)
#pragma unroll
    for (int j = 0; j < 4; ++j) {
      const int i = 4 * t + 1024 * k + j;
      float pv = (i < L) ? __expf(v[4 * k + j] - m) : 0.f;
      v[4 * k + j] = pv;
      s += pv;
    }
  for (int o = 32; o > 0; o >>= 1) s += __shfl_xor(s, o, 64);
  if ((t & 63) == 0) ss[w] = s;
  __syncthreads();
  s = ss[0] + ss[1] + ss[2] + ss[3];
  const float inv = 1.f / s;

#pragma unroll
  for (int k = 0; k < 4; ++k) {
    float4 x = make_float4(v[4 * k + 0] * inv, v[4 * k + 1] * inv,
                           v[4 * k + 2] * inv, v[4 * k + 3] * inv);
    *(float4*)&p[4 * t + 1024 * k] = x;
    *(uint2*)&q[4 * t + 1024 * k] = make_uint2(pk_bf16(x.x, x.y), pk_bf16(x.z, x.w));
  }
}

// ---------------------------------------------------------------------------
// K3: context C = Pbf . ET, pure-copy staging. M=64,N=64,KC=64, 512 blocks.
// LDS 64 rows x 8 chunks(16B), phys chunk = c ^ (row&7)  -> conflict-free.
// Waves 2x2: wave tile 32(m) x 32(n); per chunk: 8 ds_read_b128 + 8 MFMA.
// ---------------------------------------------------------------------------
__global__ __launch_bounds__(256) void k_context_pre(const short* __restrict__ Pbf,
                                                     const short* __restrict__ ET,
                                                     float* __restrict__ C) {
  const int ot = blockIdx.x, ht = blockIdx.y, b = blockIdx.z;
  const short* Pb = Pbf + ((size_t)b * OLEN + ot * 64) * (size_t)ILEN;
  const short* Tb = ET  + ((size_t)b * HDIM + ht * 64) * (size_t)ILEN;

  __shared__ __align__(16) short As[64 * 64], Bs[64 * 64];

  const int t = threadIdx.x;
  const int w = t >> 6, l = t & 63;
  const int la = l & 15, quad = l >> 4;
  const int mw = (w & 1) * 32, nw = (w >> 1) * 32;

  int sg[2], sl[2];
#pragma unroll
  for (int j = 0; j < 2; ++j) {
    const int slot = j * 256 + t;          // 16B slot, lane-ordered per wave
    const int row = slot >> 3, pc = slot & 7;
    const int c = pc ^ (row & 7);          // logical chunk this phys slot holds
    sg[j] = row * ILEN + c * 8;            // global short offset (+ic)
    sl[j] = slot * 8;                      // LDS short offset
  }

  f32x4 acc[2][2] = {};

  for (int ic = 0; ic < ILEN; ic += 64) {
#pragma unroll
    for (int j = 0; j < 2; ++j) {
      gl_lds16(&Pb[sg[j] + ic], &As[sl[j]]);
      gl_lds16(&Tb[sg[j] + ic], &Bs[sl[j]]);
    }
    __syncthreads();
    bf16x8 af[2][2], bfr[2][2];
#pragma unroll
    for (int mi = 0; mi < 2; ++mi)
#pragma unroll
      for (int ki = 0; ki < 2; ++ki) {
        const int row = mw + mi * 16 + la;
        af[mi][ki] = *(const bf16x8*)&As[row * 64 + (((ki * 4 + quad) ^ (row & 7)) * 8)];
      }
#pragma unroll
    for (int ni = 0; ni < 2; ++ni)
#pragma unroll
      for (int ki = 0; ki < 2; ++ki) {
        const int row = nw + ni * 16 + la;
        bfr[ni][ki] = *(const bf16x8*)&Bs[row * 64 + (((ki * 4 + quad) ^ (row & 7)) * 8)];
      }
#pragma unroll
    for (int mi = 0; mi < 2; ++mi)
#pragma unroll
      for (int ni = 0; ni < 2; ++ni)
#pragma unroll
        for (int ki = 0; ki < 2; ++ki)
          acc[mi][ni] = __builtin_amdgcn_mfma_f32_16x16x32_bf16(af[mi][ki], bfr[ni][ki],
                                                                acc[mi][ni], 0, 0, 0);
    __syncthreads();
  }

  float* Cb = C + ((size_t)b * OLEN + ot * 64) * HDIM + ht * 64;
#pragma unroll
  for (int mi = 0; mi < 2; ++mi)
#pragma unroll
    for (int ni = 0; ni < 2; ++ni)
#pragma unroll
      for (int r = 0; r < 4; ++r)
        Cb[(size_t)(mw + mi * 16 + quad * 4 + r) * HDIM + nw + ni * 16 + la] =
            acc[mi][ni][r];
}

// ===========================================================================
// Fallback path (ws too small) — R3-proven kernels, self-contained.
// ===========================================================================
__global__ __launch_bounds__(256) void k_etrans(const float* __restrict__ E,
                                                short* __restrict__ ET) {
  const int it = blockIdx.x, ht = blockIdx.y, b = blockIdx.z;
  __shared__ short L[32][36];
  const int t = threadIdx.x;
  {
    const int i = t >> 3, h0 = (t & 7) * 4;
    float4 v = *(const float4*)&E[((size_t)(b * ILEN + it * 32 + i)) * HDIM + ht * 32 + h0];
    L[h0 + 0][i] = f2bf(v.x);
    L[h0 + 1][i] = f2bf(v.y);
    L[h0 + 2][i] = f2bf(v.z);
    L[h0 + 3][i] = f2bf(v.w);
  }
  __syncthreads();
  {
    const int h = t >> 3, i0 = (t & 7) * 4;
    *(uint2*)&ET[((size_t)(b * HDIM + ht * 32 + h)) * ILEN + it * 32 + i0] =
        *(const uint2*)&L[h][i0];
  }
}

__global__ __launch_bounds__(256) void k_scores_split(const float* __restrict__ Q,
                                                      const float* __restrict__ E,
                                                      float* __restrict__ S) {
  const int b = blockIdx.z, ot = blockIdx.y, it = blockIdx.x;
  const float* Qb = Q + ((size_t)b * OLEN + ot * 64) * HDIM;
  const float* Eb = E + ((size_t)b * ILEN + it * 64) * HDIM;

  __shared__ __align__(16) short Ah[64 * LDA], Al[64 * LDA];
  __shared__ __align__(16) short Bh[64 * LDA], Bl[64 * LDA];

  const int t = threadIdx.x;
  const int w = t >> 6, l = t & 63;
  const int la = l & 15, quad = l >> 4;
  const int sr = t >> 2, sc = (t & 3) * 8;

  f32x4 acc[4] = {};

#pragma unroll
  for (int kc = 0; kc < HDIM; kc += 32) {
    HiLo qa = split8(&Qb[(size_t)sr * HDIM + kc + sc]);
    HiLo eb = split8(&Eb[(size_t)sr * HDIM + kc + sc]);
    *(uint4*)&Ah[sr * LDA + sc] = qa.hi;
    *(uint4*)&Al[sr * LDA + sc] = qa.lo;
    *(uint4*)&Bh[sr * LDA + sc] = eb.hi;
    *(uint4*)&Bl[sr * LDA + sc] = eb.lo;
    __syncthreads();
    bf16x8 ah = *(const bf16x8*)&Ah[(w * 16 + la) * LDA + quad * 8];
    bf16x8 al = *(const bf16x8*)&Al[(w * 16 + la) * LDA + quad * 8];
#pragma unroll
    for (int n = 0; n < 4; ++n) {
      bf16x8 bh = *(const bf16x8*)&Bh[(n * 16 + la) * LDA + quad * 8];
      bf16x8 bl = *(const bf16x8*)&Bl[(n * 16 + la) * LDA + quad * 8];
      acc[n] = __builtin_amdgcn_mfma_f32_16x16x32_bf16(ah, bh, acc[n], 0, 0, 0);
      acc[n] = __builtin_amdgcn_mfma_f32_16x16x32_bf16(ah, bl, acc[n], 0, 0, 0);
      acc[n] = __builtin_amdgcn_mfma_f32_16x16x32_bf16(al, bh, acc[n], 0, 0, 0);
    }
    __syncthreads();
  }

  float* Sb = S + ((size_t)b * OLEN + ot * 64) * (size_t)ILEN + it * 64;
#pragma unroll
  for (int n = 0; n < 4; ++n)
#pragma unroll
    for (int r = 0; r < 4; ++r)
      Sb[(size_t)(w * 16 + quad * 4 + r) * ILEN + n * 16 + la] = acc[n][r];
}

__global__ __launch_bounds__(256) void k_context_f32(const float* __restrict__ P,
                                                     const short* __restrict__ ET,
                                                     float* __restrict__ C) {
  const int ot = blockIdx.x, ht = blockIdx.y, b = blockIdx.z;
  const float* Pb = P + ((size_t)b * OLEN + ot * 64) * (size_t)ILEN;
  const short* Tb = ET + ((size_t)b * HDIM + ht * 64) * (size_t)ILEN;

  __shared__ __align__(16) short As[64 * LDA], Bs[64 * LDA];

  const int t = threadIdx.x;
  const int w = t >> 6, l = t & 63;
  const int la = l & 15, quad = l >> 4;
  const int sr = t >> 2, sc = (t & 3) * 8;

  f32x4 acc[4] = {};

  for (int ic = 0; ic < ILEN; ic += 32) {
    {
      float4 p0 = *(const float4*)&Pb[(size_t)sr * ILEN + ic + sc];
      float4 p1 = *(const float4*)&Pb[(size_t)sr * ILEN + ic + sc + 4];
      uint4 aw = make_uint4(pk_bf16(p0.x, p0.y), pk_bf16(p0.z, p0.w),
                            pk_bf16(p1.x, p1.y), pk_bf16(p1.z, p1.w));
      *(uint4*)&As[sr * LDA + sc] = aw;
      uint4 bw = *(const uint4*)&Tb[(size_t)sr * ILEN + ic + sc];
      *(uint4*)&Bs[sr * LDA + sc] = bw;
    }
    __syncthreads();
    bf16x8 a = *(const bf16x8*)&As[(w * 16 + la) * LDA + quad * 8];
#pragma unroll
    for (int n = 0; n < 4; ++n) {
      bf16x8 bb = *(const bf16x8*)&Bs[(n * 16 + la) * LDA + quad * 8];
      acc[n] = __builtin_amdgcn_mfma_f32_16x16x32_bf16(a, bb, acc[n], 0, 0, 0);
    }
    __syncthreads();
  }

  float* Cb = C + ((size_t)b * OLEN + ot * 64) * HDIM + ht * 64;
#pragma unroll
  for (int n = 0; n < 4; ++n)
#pragma unroll
    for (int r = 0; r < 4; ++r)
      Cb[(size_t)(w * 16 + quad * 4 + r) * HDIM + n * 16 + la] = acc[n][r];
}

__global__ __launch_bounds__(256) void k_softmax(float* __restrict__ A,
                                                 const int* __restrict__ len) {
  const int row = blockIdx.x;
  const int b   = row >> 10;
  const int L   = len[b];
  float* p = A + (size_t)row * ILEN;
  const int t = threadIdx.x;

  float v[16];
#pragma unroll
  for (int k = 0; k < 4; ++k) {
    float4 x = *(const float4*)&p[4 * t + 1024 * k];
    v[4 * k + 0] = x.x; v[4 * k + 1] = x.y;
    v[4 * k + 2] = x.z; v[4 * k + 3] = x.w;
  }
  float m = -INFINITY;
#pragma unroll
  for (int k = 0; k < 4; ++k)
#pragma unroll
    for (int j = 0; j < 4; ++j) {
      const int i = 4 * t + 1024 * k + j;
      if (i < L) m = fmaxf(m, v[4 * k + j]);
    }
  for (int o = 32; o > 0; o >>= 1) m = fmaxf(m, __shfl_xor(m, o, 64));
  __shared__ float sm[4], ss[4];
  const int w = t >> 6;
  if ((t & 63) == 0) sm[w] = m;
  __syncthreads();
  m = fmaxf(fmaxf(sm[0], sm[1]), fmaxf(sm[2], sm[3]));
  float s = 0.f;
#pragma unroll
  for (int k = 0; k < 4; ++k)
#pragma unroll
    for (int j = 0; j < 4; ++j) {
      const int i = 4 * t + 1024 * k + j;
      float pv = (i < L) ? __expf(v[4 * k + j] - m) : 0.f;
      v[4 * k + j] = pv;
      s += pv;
    }
  for (int o = 32; o > 0; o >>= 1) s += __shfl_xor(s, o, 64);
  if ((t & 63) == 0) ss[w] = s;
  __syncthreads();
  s = ss[0] + ss[1] + ss[2] + ss[3];
  const float inv = 1.f / s;
#pragma unroll
  for (int k = 0; k < 4; ++k) {
    float4 x = make_float4(v[4 * k + 0] * inv, v[4 * k + 1] * inv,
                           v[4 * k + 2] * inv, v[4 * k + 3] * inv);
    *(float4*)&p[4 * t + 1024 * k] = x;
  }
}

extern "C" void kernel_launch(void* const* d_in, const int* in_sizes, int n_in,
                              void* d_out, int out_size, void* d_ws, size_t ws_size,
                              hipStream_t stream) {
  (void)in_sizes; (void)n_in; (void)out_size;
  const float* outp = (const float*)d_in[0];  // [B, OLEN, H]
  const float* enc  = (const float*)d_in[1];  // [B, ILEN, H]
  const int*   len  = (const int*)d_in[2];    // [B]

  float* ctx  = (float*)d_out;
  float* attn = ctx + (size_t)B_ * OLEN * HDIM;

  short* ws = (short*)d_ws;
  const size_t M = 1024 * 1024;
  // ws layout (shorts): ET[0,8M) Qhi[8M,10M) Qlo[10M,12M) Ehi[12M,20M)
  //                     Elo[20M,28M) Pbf[28M,44M)   => 88 MB
  short* ET = ws;

  if (ws_size >= 90ull * 1024 * 1024) {
    short* Qhi = ws + 8 * M;
    short* Qlo = ws + 10 * M;
    short* Ehi = ws + 12 * M;
    short* Elo = ws + 20 * M;
    short* Pbf = ws + 28 * M;
    k_prep_q<<<(B_ * OLEN * HDIM) / (256 * 8), 256, 0, stream>>>(outp, Qhi, Qlo);
    dim3 gp(ILEN / 32, HDIM / 32, B_);
    k_prep_e<<<gp, 256, 0, stream>>>(enc, Ehi, Elo, ET);
    dim3 g1(ILEN / 128, OLEN / 128, B_);
    k_scores_pre<<<g1, 256, 0, stream>>>(Qhi, Qlo, Ehi, Elo, attn);
    k_softmax_bf<<<B_ * OLEN, 256, 0, stream>>>(attn, Pbf, len);
    dim3 g3(OLEN / 64, HDIM / 64, B_);
    k_context_pre<<<g3, 256, 0, stream>>>(Pbf, ET, ctx);
  } else {
    dim3 gt(ILEN / 32, HDIM / 32, B_);
    k_etrans<<<gt, 256, 0, stream>>>(enc, ET);
    k_scores_split<<<dim3(ILEN / 64, OLEN / 64, B_), 256, 0, stream>>>(outp, enc, attn);
    k_softmax<<<B_ * OLEN, 256, 0, stream>>>(attn, len);
    dim3 g3(OLEN / 64, HDIM / 64, B_);
    k_context_f32<<<g3, 256, 0, stream>>>(attn, ET, ctx);
  }
}

// Round 6
// 318.501 us; speedup vs baseline: 1.1286x; 1.1286x over previous
//
#include <hip/hip_runtime.h>
#include <hip/hip_bf16.h>
#include <math.h>

#define B_    8
#define OLEN  1024
#define ILEN  4096
#define HDIM  256
#define LDA   40   // fallback-path LDS row stride (shorts)

typedef __attribute__((ext_vector_type(8))) short bf16x8;
typedef __attribute__((ext_vector_type(4))) float f32x4;

__device__ inline unsigned pk_bf16(float x, float y) {
  union { __hip_bfloat162 h; unsigned u; } c;
  c.h = __float22bfloat162_rn(make_float2(x, y));
  return c.u;
}
__device__ inline short f2bf(float x) {
  union { __hip_bfloat16 h; short s; } c;
  c.h = __float2bfloat16(x);
  return c.s;
}

struct HiLo { uint4 hi, lo; };
__device__ inline HiLo split8(const float* __restrict__ p) {
  float4 v0 = *(const float4*)p;
  float4 v1 = *(const float4*)(p + 4);
  float f[8] = {v0.x, v0.y, v0.z, v0.w, v1.x, v1.y, v1.z, v1.w};
  unsigned hu[8]; float lo[8];
#pragma unroll
  for (int i = 0; i < 8; ++i) {
    unsigned u = __float_as_uint(f[i]);
    hu[i] = u & 0xffff0000u;
    lo[i] = f[i] - __uint_as_float(hu[i]);
  }
  HiLo r;
  r.hi = make_uint4((hu[0] >> 16) | hu[1], (hu[2] >> 16) | hu[3],
                    (hu[4] >> 16) | hu[5], (hu[6] >> 16) | hu[7]);
  r.lo = make_uint4(pk_bf16(lo[0], lo[1]), pk_bf16(lo[2], lo[3]),
                    pk_bf16(lo[4], lo[5]), pk_bf16(lo[6], lo[7]));
  return r;
}

__device__ inline void gl_lds16(const void* g, void* l) {
  __builtin_amdgcn_global_load_lds(
      (const __attribute__((address_space(1))) unsigned*)g,
      (__attribute__((address_space(3))) unsigned*)(l), 16, 0, 0);
}

// ---------------------------------------------------------------------------
// P0: Q -> Qhi/Qlo bf16 (linear).
// ---------------------------------------------------------------------------
__global__ __launch_bounds__(256) void k_prep_q(const float* __restrict__ Q,
                                                short* __restrict__ Qhi,
                                                short* __restrict__ Qlo) {
  const size_t idx = ((size_t)blockIdx.x * 256 + threadIdx.x) * 8;
  HiLo r = split8(&Q[idx]);
  *(uint4*)&Qhi[idx] = r.hi;
  *(uint4*)&Qlo[idx] = r.lo;
}

// ---------------------------------------------------------------------------
// P1: E -> Ehi/Elo (linear) + ET bf16 RNE transposed [b][h][i]. E read once.
// ---------------------------------------------------------------------------
__global__ __launch_bounds__(256) void k_prep_e(const float* __restrict__ E,
                                                short* __restrict__ Ehi,
                                                short* __restrict__ Elo,
                                                short* __restrict__ ET) {
  const int it = blockIdx.x, ht = blockIdx.y, b = blockIdx.z;
  __shared__ short L[32][36];
  const int t = threadIdx.x;
  {
    const int i = t >> 3, h0 = (t & 7) * 4;
    const size_t gidx = ((size_t)(b * ILEN + it * 32 + i)) * HDIM + ht * 32 + h0;
    float4 v = *(const float4*)&E[gidx];
    float f[4] = {v.x, v.y, v.z, v.w};
    unsigned hs[4]; float lo[4];
#pragma unroll
    for (int j = 0; j < 4; ++j) {
      unsigned u = __float_as_uint(f[j]);
      hs[j] = u & 0xffff0000u;
      lo[j] = f[j] - __uint_as_float(hs[j]);
    }
    *(uint2*)&Ehi[gidx] = make_uint2((hs[0] >> 16) | hs[1], (hs[2] >> 16) | hs[3]);
    *(uint2*)&Elo[gidx] = make_uint2(pk_bf16(lo[0], lo[1]), pk_bf16(lo[2], lo[3]));
    L[h0 + 0][i] = f2bf(f[0]);
    L[h0 + 1][i] = f2bf(f[1]);
    L[h0 + 2][i] = f2bf(f[2]);
    L[h0 + 3][i] = f2bf(f[3]);
  }
  __syncthreads();
  {
    const int h = t >> 3, i0 = (t & 7) * 4;
    *(uint2*)&ET[((size_t)(b * HDIM + ht * 32 + h)) * ILEN + it * 32 + i0] =
        *(const uint2*)&L[h][i0];
  }
}

// ---------------------------------------------------------------------------
// K1: scores, split-bf16 3-term MFMA, 128x128 tile, KC=32 (unchanged R4).
// ---------------------------------------------------------------------------
__global__ __launch_bounds__(256) void k_scores_pre(
    const short* __restrict__ Qhi, const short* __restrict__ Qlo,
    const short* __restrict__ Ehi, const short* __restrict__ Elo,
    float* __restrict__ S) {
  const int it = blockIdx.x, ot = blockIdx.y, b = blockIdx.z;
  const size_t qoff = ((size_t)b * OLEN + ot * 128) * HDIM;
  const size_t eoff = ((size_t)b * ILEN + it * 128) * HDIM;

  __shared__ __align__(16) short Ah[128 * 32], Al[128 * 32];
  __shared__ __align__(16) short Bh[128 * 32], Bl[128 * 32];

  const int t = threadIdx.x;
  const int w = t >> 6, l = t & 63;
  const int la = l & 15, quad = l >> 4;
  const int mw = (w & 1) * 64, nw = (w >> 1) * 64;

  int sgoff[2], sloff[2];
#pragma unroll
  for (int j = 0; j < 2; ++j) {
    const int row = (w * 2 + j) * 16 + (l >> 2);
    const int c = (l & 3) ^ ((row >> 1) & 3);
    sgoff[j] = row * HDIM + c * 8;
    sloff[j] = ((w * 2 + j) * 64 + l) * 8;
  }

  f32x4 acc[4][4] = {};

  for (int kc = 0; kc < HDIM; kc += 32) {
#pragma unroll
    for (int j = 0; j < 2; ++j) {
      const size_t ga = qoff + sgoff[j] + kc;
      const size_t gb = eoff + sgoff[j] + kc;
      gl_lds16(&Qhi[ga], &Ah[sloff[j]]);
      gl_lds16(&Qlo[ga], &Al[sloff[j]]);
      gl_lds16(&Ehi[gb], &Bh[sloff[j]]);
      gl_lds16(&Elo[gb], &Bl[sloff[j]]);
    }
    __syncthreads();
    bf16x8 ah[4], al[4];
#pragma unroll
    for (int mi = 0; mi < 4; ++mi) {
      const int row = mw + mi * 16 + la;
      const int off = row * 32 + (quad ^ ((row >> 1) & 3)) * 8;
      ah[mi] = *(const bf16x8*)&Ah[off];
      al[mi] = *(const bf16x8*)&Al[off];
    }
#pragma unroll
    for (int ni = 0; ni < 4; ++ni) {
      const int row = nw + ni * 16 + la;
      const int off = row * 32 + (quad ^ ((row >> 1) & 3)) * 8;
      bf16x8 bh = *(const bf16x8*)&Bh[off];
      bf16x8 bl = *(const bf16x8*)&Bl[off];
#pragma unroll
      for (int mi = 0; mi < 4; ++mi) {
        acc[mi][ni] = __builtin_amdgcn_mfma_f32_16x16x32_bf16(ah[mi], bh, acc[mi][ni], 0, 0, 0);
        acc[mi][ni] = __builtin_amdgcn_mfma_f32_16x16x32_bf16(ah[mi], bl, acc[mi][ni], 0, 0, 0);
        acc[mi][ni] = __builtin_amdgcn_mfma_f32_16x16x32_bf16(al[mi], bh, acc[mi][ni], 0, 0, 0);
      }
    }
    __syncthreads();
  }

  float* Sb = S + ((size_t)b * OLEN + ot * 128) * (size_t)ILEN + it * 128;
#pragma unroll
  for (int mi = 0; mi < 4; ++mi)
#pragma unroll
    for (int ni = 0; ni < 4; ++ni)
#pragma unroll
      for (int r = 0; r < 4; ++r)
        Sb[(size_t)(mw + mi * 16 + quad * 4 + r) * ILEN + nw + ni * 16 + la] =
            acc[mi][ni][r];
}

// ---------------------------------------------------------------------------
// K2: in-place masked row softmax (R4-proven, no Pbf).
// ---------------------------------------------------------------------------
__global__ __launch_bounds__(256) void k_softmax(float* __restrict__ A,
                                                 const int* __restrict__ len) {
  const int row = blockIdx.x;
  const int b   = row >> 10;
  const int L   = len[b];
  float* p = A + (size_t)row * ILEN;
  const int t = threadIdx.x;

  float v[16];
#pragma unroll
  for (int k = 0; k < 4; ++k) {
    float4 x = *(const float4*)&p[4 * t + 1024 * k];
    v[4 * k + 0] = x.x; v[4 * k + 1] = x.y;
    v[4 * k + 2] = x.z; v[4 * k + 3] = x.w;
  }
  float m = -INFINITY;
#pragma unroll
  for (int k = 0; k < 4; ++k)
#pragma unroll
    for (int j = 0; j < 4; ++j) {
      const int i = 4 * t + 1024 * k + j;
      if (i < L) m = fmaxf(m, v[4 * k + j]);
    }
  for (int o = 32; o > 0; o >>= 1) m = fmaxf(m, __shfl_xor(m, o, 64));
  __shared__ float sm[4], ss[4];
  const int w = t >> 6;
  if ((t & 63) == 0) sm[w] = m;
  __syncthreads();
  m = fmaxf(fmaxf(sm[0], sm[1]), fmaxf(sm[2], sm[3]));
  float s = 0.f;
#pragma unroll
  for (int k = 0; k < 4; ++k)
#pragma unroll
    for (int j = 0; j < 4; ++j) {
      const int i = 4 * t + 1024 * k + j;
      float pv = (i < L) ? __expf(v[4 * k + j] - m) : 0.f;
      v[4 * k + j] = pv;
      s += pv;
    }
  for (int o = 32; o > 0; o >>= 1) s += __shfl_xor(s, o, 64);
  if ((t & 63) == 0) ss[w] = s;
  __syncthreads();
  s = ss[0] + ss[1] + ss[2] + ss[3];
  const float inv = 1.f / s;
#pragma unroll
  for (int k = 0; k < 4; ++k) {
    float4 x = make_float4(v[4 * k + 0] * inv, v[4 * k + 1] * inv,
                           v[4 * k + 2] * inv, v[4 * k + 3] * inv);
    *(float4*)&p[4 * t + 1024 * k] = x;
  }
}

// ---------------------------------------------------------------------------
// K3 v3: context partial. M=64, N=256(full H), K-split=2, KC=64.
// Grid (16 ot, 2 ks, 8 b) = 256 blocks. P read ONCE (fp32, convert in staging);
// ET staged via global_load_lds. LDS rows of 8x16B chunks, phys = c ^ (row&7).
// Wave w: m-half (w&1)*32, n-half (w>>1)*128. 32 MFMA : 20 ds_read per chunk.
// ---------------------------------------------------------------------------
__global__ __launch_bounds__(256) void k_context_v3(const float* __restrict__ P,
                                                    const short* __restrict__ ET,
                                                    float* __restrict__ Cpart) {
  const int ot = blockIdx.x, ks = blockIdx.y, b = blockIdx.z;
  const float* Pb = P + ((size_t)b * OLEN + ot * 64) * (size_t)ILEN + ks * 2048;
  const short* Tb = ET + (size_t)b * HDIM * ILEN + ks * 2048;

  __shared__ __align__(16) short As[64 * 64];    // [o-row][i] 8 chunks/row
  __shared__ __align__(16) short Bs[256 * 64];   // [h-row][i] 8 chunks/row

  const int t = threadIdx.x;
  const int w = t >> 6, l = t & 63;
  const int la = l & 15, quad = l >> 4;
  const int mw = (w & 1) * 32, nw = (w >> 1) * 128;

  // A staging map: thread t -> row tr, two 16B chunks c0,c0+1
  const int tr = t >> 2, tc = t & 3;             // row 0..63, col-quarter
  const int ac0 = tc * 2;
  // B staging map: 8 gl_lds insts/thread; wave-uniform LDS bases
  int bslot[8];
#pragma unroll
  for (int j = 0; j < 8; ++j) bslot[j] = w * 512 + j * 64 + l;  // 16B slot id

  f32x4 acc[2][8] = {};

  for (int ic = 0; ic < 2048; ic += 64) {
    // --- stage B (pure copy, async) ---
#pragma unroll
    for (int j = 0; j < 8; ++j) {
      const int s = bslot[j];
      const int row = s >> 3, pc = s & 7;
      const int c = pc ^ (row & 7);
      gl_lds16(&Tb[(size_t)row * ILEN + ic + c * 8], &Bs[s * 8]);
    }
    // --- stage A (fp32 -> bf16 convert) ---
    {
      const float* src = &Pb[(size_t)tr * ILEN + ic + tc * 16];
      float4 f0 = *(const float4*)src;
      float4 f1 = *(const float4*)(src + 4);
      float4 f2 = *(const float4*)(src + 8);
      float4 f3 = *(const float4*)(src + 12);
      uint4 w0 = make_uint4(pk_bf16(f0.x, f0.y), pk_bf16(f0.z, f0.w),
                            pk_bf16(f1.x, f1.y), pk_bf16(f1.z, f1.w));
      uint4 w1 = make_uint4(pk_bf16(f2.x, f2.y), pk_bf16(f2.z, f2.w),
                            pk_bf16(f3.x, f3.y), pk_bf16(f3.z, f3.w));
      *(uint4*)&As[tr * 64 + ((ac0) ^ (tr & 7)) * 8] = w0;
      *(uint4*)&As[tr * 64 + ((ac0 + 1) ^ (tr & 7)) * 8] = w1;
    }
    __syncthreads();
    // --- MFMA ---
#pragma unroll
    for (int ki = 0; ki < 2; ++ki) {
      bf16x8 af[2];
#pragma unroll
      for (int mi = 0; mi < 2; ++mi) {
        const int row = mw + mi * 16 + la;
        af[mi] = *(const bf16x8*)&As[row * 64 + ((ki * 4 + quad) ^ (row & 7)) * 8];
      }
#pragma unroll
      for (int ni = 0; ni < 8; ++ni) {
        const int row = nw + ni * 16 + la;
        bf16x8 bfr = *(const bf16x8*)&Bs[row * 64 + ((ki * 4 + quad) ^ (row & 7)) * 8];
#pragma unroll
        for (int mi = 0; mi < 2; ++mi)
          acc[mi][ni] = __builtin_amdgcn_mfma_f32_16x16x32_bf16(af[mi], bfr,
                                                               acc[mi][ni], 0, 0, 0);
      }
    }
    __syncthreads();
  }

  float* Cb = Cpart + (size_t)ks * (B_ * OLEN * HDIM) +
              ((size_t)b * OLEN + ot * 64) * HDIM;
#pragma unroll
  for (int mi = 0; mi < 2; ++mi)
#pragma unroll
    for (int ni = 0; ni < 8; ++ni)
#pragma unroll
      for (int r = 0; r < 4; ++r)
        Cb[(size_t)(mw + mi * 16 + quad * 4 + r) * HDIM + nw + ni * 16 + la] =
            acc[mi][ni][r];
}

// K4: ctx = Cpart[0] + Cpart[1]
__global__ __launch_bounds__(256) void k_reduce(const float* __restrict__ Cp,
                                                float* __restrict__ ctx) {
  const size_t idx = ((size_t)blockIdx.x * 256 + threadIdx.x) * 8;
  const size_t n = (size_t)B_ * OLEN * HDIM;
  float4 a0 = *(const float4*)&Cp[idx];
  float4 a1 = *(const float4*)&Cp[idx + 4];
  float4 b0 = *(const float4*)&Cp[n + idx];
  float4 b1 = *(const float4*)&Cp[n + idx + 4];
  *(float4*)&ctx[idx] = make_float4(a0.x + b0.x, a0.y + b0.y, a0.z + b0.z, a0.w + b0.w);
  *(float4*)&ctx[idx + 4] = make_float4(a1.x + b1.x, a1.y + b1.y, a1.z + b1.z, a1.w + b1.w);
}

// ===========================================================================
// Fallback path (ws too small) — R3-proven kernels.
// ===========================================================================
__global__ __launch_bounds__(256) void k_etrans(const float* __restrict__ E,
                                                short* __restrict__ ET) {
  const int it = blockIdx.x, ht = blockIdx.y, b = blockIdx.z;
  __shared__ short L[32][36];
  const int t = threadIdx.x;
  {
    const int i = t >> 3, h0 = (t & 7) * 4;
    float4 v = *(const float4*)&E[((size_t)(b * ILEN + it * 32 + i)) * HDIM + ht * 32 + h0];
    L[h0 + 0][i] = f2bf(v.x);
    L[h0 + 1][i] = f2bf(v.y);
    L[h0 + 2][i] = f2bf(v.z);
    L[h0 + 3][i] = f2bf(v.w);
  }
  __syncthreads();
  {
    const int h = t >> 3, i0 = (t & 7) * 4;
    *(uint2*)&ET[((size_t)(b * HDIM + ht * 32 + h)) * ILEN + it * 32 + i0] =
        *(const uint2*)&L[h][i0];
  }
}

__global__ __launch_bounds__(256) void k_scores_split(const float* __restrict__ Q,
                                                      const float* __restrict__ E,
                                                      float* __restrict__ S) {
  const int b = blockIdx.z, ot = blockIdx.y, it = blockIdx.x;
  const float* Qb = Q + ((size_t)b * OLEN + ot * 64) * HDIM;
  const float* Eb = E + ((size_t)b * ILEN + it * 64) * HDIM;

  __shared__ __align__(16) short Ah[64 * LDA], Al[64 * LDA];
  __shared__ __align__(16) short Bh[64 * LDA], Bl[64 * LDA];

  const int t = threadIdx.x;
  const int w = t >> 6, l = t & 63;
  const int la = l & 15, quad = l >> 4;
  const int sr = t >> 2, sc = (t & 3) * 8;

  f32x4 acc[4] = {};

#pragma unroll
  for (int kc = 0; kc < HDIM; kc += 32) {
    HiLo qa = split8(&Qb[(size_t)sr * HDIM + kc + sc]);
    HiLo eb = split8(&Eb[(size_t)sr * HDIM + kc + sc]);
    *(uint4*)&Ah[sr * LDA + sc] = qa.hi;
    *(uint4*)&Al[sr * LDA + sc] = qa.lo;
    *(uint4*)&Bh[sr * LDA + sc] = eb.hi;
    *(uint4*)&Bl[sr * LDA + sc] = eb.lo;
    __syncthreads();
    bf16x8 ah = *(const bf16x8*)&Ah[(w * 16 + la) * LDA + quad * 8];
    bf16x8 al = *(const bf16x8*)&Al[(w * 16 + la) * LDA + quad * 8];
#pragma unroll
    for (int n = 0; n < 4; ++n) {
      bf16x8 bh = *(const bf16x8*)&Bh[(n * 16 + la) * LDA + quad * 8];
      bf16x8 bl = *(const bf16x8*)&Bl[(n * 16 + la) * LDA + quad * 8];
      acc[n] = __builtin_amdgcn_mfma_f32_16x16x32_bf16(ah, bh, acc[n], 0, 0, 0);
      acc[n] = __builtin_amdgcn_mfma_f32_16x16x32_bf16(ah, bl, acc[n], 0, 0, 0);
      acc[n] = __builtin_amdgcn_mfma_f32_16x16x32_bf16(al, bh, acc[n], 0, 0, 0);
    }
    __syncthreads();
  }

  float* Sb = S + ((size_t)b * OLEN + ot * 64) * (size_t)ILEN + it * 64;
#pragma unroll
  for (int n = 0; n < 4; ++n)
#pragma unroll
    for (int r = 0; r < 4; ++r)
      Sb[(size_t)(w * 16 + quad * 4 + r) * ILEN + n * 16 + la] = acc[n][r];
}

__global__ __launch_bounds__(256) void k_context_f32(const float* __restrict__ P,
                                                     const short* __restrict__ ET,
                                                     float* __restrict__ C) {
  const int ot = blockIdx.x, ht = blockIdx.y, b = blockIdx.z;
  const float* Pb = P + ((size_t)b * OLEN + ot * 64) * (size_t)ILEN;
  const short* Tb = ET + ((size_t)b * HDIM + ht * 64) * (size_t)ILEN;

  __shared__ __align__(16) short As[64 * LDA], Bs[64 * LDA];

  const int t = threadIdx.x;
  const int w = t >> 6, l = t & 63;
  const int la = l & 15, quad = l >> 4;
  const int sr = t >> 2, sc = (t & 3) * 8;

  f32x4 acc[4] = {};

  for (int ic = 0; ic < ILEN; ic += 32) {
    {
      float4 p0 = *(const float4*)&Pb[(size_t)sr * ILEN + ic + sc];
      float4 p1 = *(const float4*)&Pb[(size_t)sr * ILEN + ic + sc + 4];
      uint4 aw = make_uint4(pk_bf16(p0.x, p0.y), pk_bf16(p0.z, p0.w),
                            pk_bf16(p1.x, p1.y), pk_bf16(p1.z, p1.w));
      *(uint4*)&As[sr * LDA + sc] = aw;
      uint4 bw = *(const uint4*)&Tb[(size_t)sr * ILEN + ic + sc];
      *(uint4*)&Bs[sr * LDA + sc] = bw;
    }
    __syncthreads();
    bf16x8 a = *(const bf16x8*)&As[(w * 16 + la) * LDA + quad * 8];
#pragma unroll
    for (int n = 0; n < 4; ++n) {
      bf16x8 bb = *(const bf16x8*)&Bs[(n * 16 + la) * LDA + quad * 8];
      acc[n] = __builtin_amdgcn_mfma_f32_16x16x32_bf16(a, bb, acc[n], 0, 0, 0);
    }
    __syncthreads();
  }

  float* Cb = C + ((size_t)b * OLEN + ot * 64) * HDIM + ht * 64;
#pragma unroll
  for (int n = 0; n < 4; ++n)
#pragma unroll
    for (int r = 0; r < 4; ++r)
      Cb[(size_t)(w * 16 + quad * 4 + r) * HDIM + n * 16 + la] = acc[n][r];
}

extern "C" void kernel_launch(void* const* d_in, const int* in_sizes, int n_in,
                              void* d_out, int out_size, void* d_ws, size_t ws_size,
                              hipStream_t stream) {
  (void)in_sizes; (void)n_in; (void)out_size;
  const float* outp = (const float*)d_in[0];  // [B, OLEN, H]
  const float* enc  = (const float*)d_in[1];  // [B, ILEN, H]
  const int*   len  = (const int*)d_in[2];    // [B]

  float* ctx  = (float*)d_out;
  float* attn = ctx + (size_t)B_ * OLEN * HDIM;

  short* ws = (short*)d_ws;
  const size_t M = 1024 * 1024;
  // ws layout (shorts): ET[0,8M) Qhi[8M,10M) Qlo[10M,12M) Ehi[12M,20M) Elo[20M,28M)
  // = 56 MB total (proven available in R4). Cpart (fp32, 2x8.4MB) overlays the
  // dead Qhi/Qlo/Ehi region (bytes [16M, 49.6M)) after k_scores_pre completes.
  short* ET = ws;

  if (ws_size >= 56ull * 1024 * 1024) {
    short* Qhi = ws + 8 * M;
    short* Qlo = ws + 10 * M;
    short* Ehi = ws + 12 * M;
    short* Elo = ws + 20 * M;
    float* Cpart = (float*)(ws + 8 * M);  // byte offset 16 MB; 33.6 MB used
    k_prep_q<<<(B_ * OLEN * HDIM) / (256 * 8), 256, 0, stream>>>(outp, Qhi, Qlo);
    dim3 gp(ILEN / 32, HDIM / 32, B_);
    k_prep_e<<<gp, 256, 0, stream>>>(enc, Ehi, Elo, ET);
    dim3 g1(ILEN / 128, OLEN / 128, B_);
    k_scores_pre<<<g1, 256, 0, stream>>>(Qhi, Qlo, Ehi, Elo, attn);
    k_softmax<<<B_ * OLEN, 256, 0, stream>>>(attn, len);
    dim3 g3(OLEN / 64, 2, B_);
    k_context_v3<<<g3, 256, 0, stream>>>(attn, ET, Cpart);
    k_reduce<<<(B_ * OLEN * HDIM) / (256 * 8), 256, 0, stream>>>(Cpart, ctx);
  } else {
    dim3 gt(ILEN / 32, HDIM / 32, B_);
    k_etrans<<<gt, 256, 0, stream>>>(enc, ET);
    k_scores_split<<<dim3(ILEN / 64, OLEN / 64, B_), 256, 0, stream>>>(outp, enc, attn);
    k_softmax<<<B_ * OLEN, 256, 0, stream>>>(attn, len);
    dim3 g3(OLEN / 64, HDIM / 64, B_);
    k_context_f32<<<g3, 256, 0, stream>>>(attn, ET, ctx);
  }
}